// Round 1
// baseline (164.547 us; speedup 1.0000x reference)
//
#include <hip/hip_runtime.h>

#define BINS 4096  // 16^3

__device__ __forceinline__ int qz(float c) {
    // matches: clip((c * 15.0f).astype(int32), 0, 15); c >= 0 so trunc == floor
    int q = (int)(c * 15.0f);
    q = q < 0 ? 0 : q;
    q = q > 15 ? 15 : q;
    return q;
}

__device__ __forceinline__ int bin3(float r, float g, float b) {
    return (qz(r) * 16 + qz(g)) * 16 + qz(b);
}

// Histogram of source colors: per-block LDS histogram, flush via global atomics.
// Points are loaded as 3x float4 = 4 points per iteration (coalesced 16B/lane).
__global__ __launch_bounds__(256) void src_hist_kernel(const float* __restrict__ src,
                                                       unsigned int* __restrict__ g_hist,
                                                       int n_pts) {
    __shared__ unsigned int lhist[BINS];
    for (int i = threadIdx.x; i < BINS; i += blockDim.x) lhist[i] = 0;
    __syncthreads();

    const float4* __restrict__ src4 = (const float4*)src;
    const int n_quads = n_pts >> 2;  // groups of 4 points = 12 floats = 3 float4
    const int tid = blockIdx.x * blockDim.x + threadIdx.x;
    const int stride = gridDim.x * blockDim.x;

    for (int q = tid; q < n_quads; q += stride) {
        float4 a = src4[3 * q + 0];
        float4 b = src4[3 * q + 1];
        float4 c = src4[3 * q + 2];
        // point 0: a.x a.y a.z | point 1: a.w b.x b.y | point 2: b.z b.w c.x | point 3: c.y c.z c.w
        atomicAdd(&lhist[bin3(a.x, a.y, a.z)], 1u);
        atomicAdd(&lhist[bin3(a.w, b.x, b.y)], 1u);
        atomicAdd(&lhist[bin3(b.z, b.w, c.x)], 1u);
        atomicAdd(&lhist[bin3(c.y, c.z, c.w)], 1u);
    }

    // tail (n_pts not divisible by 4) — handled by block 0 only
    if (blockIdx.x == 0) {
        int tail = n_pts & 3;
        if ((int)threadIdx.x < tail) {
            int p = (n_quads << 2) + threadIdx.x;
            atomicAdd(&lhist[bin3(src[3 * p], src[3 * p + 1], src[3 * p + 2])], 1u);
        }
    }

    __syncthreads();
    for (int i = threadIdx.x; i < BINS; i += blockDim.x) {
        unsigned int v = lhist[i];
        if (v) atomicAdd(&g_hist[i], v);
    }
}

// Single block: build target histogram in LDS, then L1 distance vs source hist.
__global__ __launch_bounds__(512) void loss_kernel(const float* __restrict__ tgt,
                                                   const unsigned int* __restrict__ g_hist,
                                                   float* __restrict__ out,
                                                   int n_src, int n_tgt) {
    __shared__ unsigned int thist[BINS];
    for (int i = threadIdx.x; i < BINS; i += blockDim.x) thist[i] = 0;
    __syncthreads();

    const float4* __restrict__ t4 = (const float4*)tgt;
    const int n_quads = n_tgt >> 2;
    for (int q = threadIdx.x; q < n_quads; q += blockDim.x) {
        float4 a = t4[3 * q + 0];
        float4 b = t4[3 * q + 1];
        float4 c = t4[3 * q + 2];
        atomicAdd(&thist[bin3(a.x, a.y, a.z)], 1u);
        atomicAdd(&thist[bin3(a.w, b.x, b.y)], 1u);
        atomicAdd(&thist[bin3(b.z, b.w, c.x)], 1u);
        atomicAdd(&thist[bin3(c.y, c.z, c.w)], 1u);
    }
    {
        int tail = n_tgt & 3;
        if ((int)threadIdx.x < tail) {
            int p = (n_quads << 2) + threadIdx.x;
            atomicAdd(&thist[bin3(tgt[3 * p], tgt[3 * p + 1], tgt[3 * p + 2])], 1u);
        }
    }
    __syncthreads();

    const double ns = (double)n_src + 1e-8;
    const double nt = (double)n_tgt + 1e-8;
    double acc = 0.0;
    for (int i = threadIdx.x; i < BINS; i += blockDim.x) {
        double s = (double)g_hist[i] / ns;
        double t = (double)thist[i] / nt;
        acc += fabs(s - t);
    }

    // wave (64-lane) shuffle reduction, then cross-wave via LDS
    for (int off = 32; off > 0; off >>= 1) acc += __shfl_down(acc, off);
    __shared__ double red[8];  // 512 / 64 waves
    const int lane = threadIdx.x & 63;
    const int wave = threadIdx.x >> 6;
    if (lane == 0) red[wave] = acc;
    __syncthreads();
    if (threadIdx.x == 0) {
        double s = 0.0;
        const int nwaves = (int)(blockDim.x >> 6);
        for (int w = 0; w < nwaves; ++w) s += red[w];
        out[0] = (float)(s / (double)BINS);
    }
}

extern "C" void kernel_launch(void* const* d_in, const int* in_sizes, int n_in,
                              void* d_out, int out_size, void* d_ws, size_t ws_size,
                              hipStream_t stream) {
    const float* src = (const float*)d_in[0];
    const float* tgt = (const float*)d_in[1];
    const int n_src = in_sizes[0] / 3;
    const int n_tgt = in_sizes[1] / 3;

    unsigned int* g_hist = (unsigned int*)d_ws;  // 4096 * 4 B = 16 KB

    hipMemsetAsync(g_hist, 0, BINS * sizeof(unsigned int), stream);
    src_hist_kernel<<<1024, 256, 0, stream>>>(src, g_hist, n_src);
    loss_kernel<<<1, 512, 0, stream>>>(tgt, g_hist, (float*)d_out, n_src, n_tgt);
}